// Round 2
// baseline (429.810 us; speedup 1.0000x reference)
//
#include <hip/hip_runtime.h>
#include <math.h>

#define N_NODESC 50000
#define N_EDGESC 800000

// ---------------------------------------------------------------------------
// edge_index may arrive as int64 (reference dtype) or int32 (JAX no-x64 /
// harness conversion). A detect kernel sets *flag = 1 iff the buffer is
// int64 (all high 32-bit words of the first 64 values are zero).
// ---------------------------------------------------------------------------
__device__ __forceinline__ int edge_val(const void* ei, long long idx, int is64) {
  if (is64) return (int)((const long long*)ei)[idx];
  return ((const int*)ei)[idx];
}

__global__ void k_detect(const unsigned int* __restrict__ ei, int* __restrict__ flag) {
  unsigned int v = ei[2 * threadIdx.x + 1];
  unsigned long long m = __ballot(v == 0u);
  if (threadIdx.x == 0) *flag = (m == ~0ull) ? 1 : 0;
}

// histogram of incoming edges per dst node
__global__ void k_count(const void* __restrict__ ei, const int* __restrict__ flag,
                        int* __restrict__ cnt) {
  int e = blockIdx.x * blockDim.x + threadIdx.x;
  if (e >= N_EDGESC) return;
  int is64 = *flag;
  int d = edge_val(ei, (long long)N_EDGESC + e, is64);
  atomicAdd(&cnt[d], 1);
}

// per-block inclusive scan (Hillis-Steele over 1024) -> off[i+1], block sums
__global__ void k_scan1(const int* __restrict__ cnt, int* __restrict__ off,
                        int* __restrict__ bsum) {
  __shared__ int sh[1024];
  int i = blockIdx.x * 1024 + threadIdx.x;
  int v = (i < N_NODESC) ? cnt[i] : 0;
  sh[threadIdx.x] = v;
  __syncthreads();
  for (int s = 1; s < 1024; s <<= 1) {
    int t = (threadIdx.x >= s) ? sh[threadIdx.x - s] : 0;
    __syncthreads();
    sh[threadIdx.x] += t;
    __syncthreads();
  }
  if (i < N_NODESC) off[i + 1] = sh[threadIdx.x];
  if (threadIdx.x == 1023) bsum[blockIdx.x] = sh[1023];
}

// single-wave scan of the (<=64) block sums, inclusive, in place
__global__ void k_scan2(int* __restrict__ bsum, int nb) {
  int lane = threadIdx.x;
  int v = (lane < nb) ? bsum[lane] : 0;
  for (int s = 1; s < 64; s <<= 1) {
    int t = __shfl_up(v, s, 64);
    if (lane >= s) v += t;
  }
  if (lane < nb) bsum[lane] = v;
}

// add block-prefix, set off[0] = 0
__global__ void k_scan3(int* __restrict__ off, const int* __restrict__ bsum) {
  int i = blockIdx.x * blockDim.x + threadIdx.x;
  if (i == 0) off[0] = 0;
  if (i >= N_NODESC) return;
  int b = i >> 10;
  if (b > 0) off[i + 1] += bsum[b - 1];
}

// dinv = rsqrt(in_count + 1 [self loop]); cursor = off (for CSR fill)
__global__ void k_prep(const int* __restrict__ cnt, const int* __restrict__ off,
                       float* __restrict__ dinv, int* __restrict__ cursor) {
  int i = blockIdx.x * blockDim.x + threadIdx.x;
  if (i >= N_NODESC) return;
  dinv[i] = rsqrtf((float)(cnt[i] + 1));
  cursor[i] = off[i];
}

// scatter edges into CSR-by-dst (order within a node irrelevant: fp sum assoc)
__global__ void k_fill(const void* __restrict__ ei, const int* __restrict__ flag,
                       int* __restrict__ cursor, int* __restrict__ csr) {
  int e = blockIdx.x * blockDim.x + threadIdx.x;
  if (e >= N_EDGESC) return;
  int is64 = *flag;
  int d = edge_val(ei, (long long)N_EDGESC + e, is64);
  int s = edge_val(ei, e, is64);
  int p = atomicAdd(&cursor[d], 1);
  csr[p] = s;
}

// ---------------------------------------------------------------------------
// T = X @ W   (rows x 128 @ 128x128, fp32 vector ALU; W + 16-row x-tile in LDS)
// 256 threads: f = tid&127, row-group = tid>>7; each thread 8 rows x 1 feat.
// ---------------------------------------------------------------------------
__global__ __launch_bounds__(256) void k_gemm(const float* __restrict__ X,
                                              const float* __restrict__ W,
                                              float* __restrict__ T, int rpb) {
  __shared__ float Wl[128 * 128];
  __shared__ float xs[16][128];
  for (int i = threadIdx.x; i < 128 * 128; i += 256) Wl[i] = W[i];
  int f = threadIdx.x & 127;
  int rg = threadIdx.x >> 7;
  int row0 = blockIdx.x * rpb;
  int rend = min(row0 + rpb, N_NODESC);
  for (int rb = row0; rb < rend; rb += 16) {
    int nr = min(16, rend - rb);
    __syncthreads();  // xs reuse + (first iter) Wl visibility
    for (int i = threadIdx.x; i < nr * 128; i += 256)
      xs[i >> 7][i & 127] = X[(long long)(rb + (i >> 7)) * 128 + (i & 127)];
    __syncthreads();
    float acc[8] = {0.f, 0.f, 0.f, 0.f, 0.f, 0.f, 0.f, 0.f};
    for (int k = 0; k < 128; k += 4) {
      float w0 = Wl[(k + 0) * 128 + f];
      float w1 = Wl[(k + 1) * 128 + f];
      float w2 = Wl[(k + 2) * 128 + f];
      float w3 = Wl[(k + 3) * 128 + f];
#pragma unroll
      for (int rr = 0; rr < 8; ++rr) {
        const float4 xv = *(const float4*)&xs[rg * 8 + rr][k];
        acc[rr] = fmaf(xv.x, w0, acc[rr]);
        acc[rr] = fmaf(xv.y, w1, acc[rr]);
        acc[rr] = fmaf(xv.z, w2, acc[rr]);
        acc[rr] = fmaf(xv.w, w3, acc[rr]);
      }
    }
#pragma unroll
    for (int rr = 0; rr < 8; ++rr) {
      int r = rg * 8 + rr;
      if (r < nr) T[(long long)(rb + r) * 128 + f] = acc[rr];
    }
  }
}

// ---------------------------------------------------------------------------
// Aggregation: one wave per dst node, 2 features per lane.
// out[d] = relu( dinv[d]*( sum_{s in in(d)} dinv[s]*T[s] + dinv[d]*T[d] ) + b )
// FINAL=1 additionally fuses the 128->1 projection + sigmoid.
// Edge loop unrolled x2: two independent gather chains in flight.
// ---------------------------------------------------------------------------
template <int FINAL>
__global__ __launch_bounds__(256) void k_agg(const float* __restrict__ T,
                                             const int* __restrict__ off,
                                             const int* __restrict__ csr,
                                             const float* __restrict__ dinv,
                                             const float* __restrict__ bias,
                                             const float* __restrict__ wout,
                                             const float* __restrict__ bout,
                                             float* __restrict__ outp) {
  int gid = blockIdx.x * blockDim.x + threadIdx.x;
  int wid = gid >> 6;
  int lane = threadIdx.x & 63;
  if (wid >= N_NODESC) return;
  int d = wid;
  float dv = dinv[d];
  int e0 = off[d], e1 = off[d + 1];
  const float* Trow = T + (long long)d * 128;
  float a0 = dv * Trow[lane];
  float a1 = dv * Trow[lane + 64];
  int e = e0;
  for (; e + 1 < e1; e += 2) {
    int s0 = csr[e];
    int s1 = csr[e + 1];
    float w0 = dinv[s0];
    float w1 = dinv[s1];
    const float* Ts0 = T + (long long)s0 * 128;
    const float* Ts1 = T + (long long)s1 * 128;
    float t00 = Ts0[lane];
    float t01 = Ts0[lane + 64];
    float t10 = Ts1[lane];
    float t11 = Ts1[lane + 64];
    a0 = fmaf(w0, t00, a0);
    a1 = fmaf(w0, t01, a1);
    a0 = fmaf(w1, t10, a0);
    a1 = fmaf(w1, t11, a1);
  }
  if (e < e1) {
    int s = csr[e];
    float w = dinv[s];
    const float* Ts = T + (long long)s * 128;
    a0 = fmaf(w, Ts[lane], a0);
    a1 = fmaf(w, Ts[lane + 64], a1);
  }
  a0 = fmaxf(fmaf(a0, dv, bias[lane]), 0.f);
  a1 = fmaxf(fmaf(a1, dv, bias[lane + 64]), 0.f);
  if (FINAL) {
    float r = a0 * wout[lane] + a1 * wout[lane + 64];
#pragma unroll
    for (int s2 = 32; s2 > 0; s2 >>= 1) r += __shfl_xor(r, s2, 64);
    if (lane == 0) outp[d] = 1.f / (1.f + __expf(-(r + bout[0])));
  } else {
    outp[(long long)d * 128 + lane] = a0;
    outp[(long long)d * 128 + lane + 64] = a1;
  }
}

// ---------------------------------------------------------------------------
extern "C" void kernel_launch(void* const* d_in, const int* in_sizes, int n_in,
                              void* d_out, int out_size, void* d_ws, size_t ws_size,
                              hipStream_t stream) {
  const float* x  = (const float*)d_in[0];
  const void*  ei = d_in[1];
  const float* W1 = (const float*)d_in[2];
  const float* b1 = (const float*)d_in[3];
  const float* W2 = (const float*)d_in[4];
  const float* b2 = (const float*)d_in[5];
  const float* Wo = (const float*)d_in[6];
  const float* bo = (const float*)d_in[7];
  float* out = (float*)d_out;

  char* p = (char*)d_ws;
  auto alloc = [&](size_t bytes) {
    char* r = p;
    p += (bytes + 511) & ~(size_t)511;
    return r;
  };
  int*   flag   = (int*)alloc(sizeof(int));
  int*   cnt    = (int*)alloc(sizeof(int) * N_NODESC);
  int*   off    = (int*)alloc(sizeof(int) * (N_NODESC + 1));
  int*   cursor = (int*)alloc(sizeof(int) * N_NODESC);
  int*   bsum   = (int*)alloc(sizeof(int) * 64);
  float* dinv   = (float*)alloc(sizeof(float) * N_NODESC);
  int*   csr    = (int*)alloc(sizeof(int) * N_EDGESC);
  float* T      = (float*)alloc(sizeof(float) * N_NODESC * 128);
  float* H      = (float*)alloc(sizeof(float) * N_NODESC * 128);

  hipMemsetAsync(cnt, 0, sizeof(int) * N_NODESC, stream);
  k_detect<<<1, 64, 0, stream>>>((const unsigned int*)ei, flag);
  k_count<<<(N_EDGESC + 255) / 256, 256, 0, stream>>>(ei, flag, cnt);
  int nb = (N_NODESC + 1023) / 1024;  // 49
  k_scan1<<<nb, 1024, 0, stream>>>(cnt, off, bsum);
  k_scan2<<<1, 64, 0, stream>>>(bsum, nb);
  k_scan3<<<(N_NODESC + 255) / 256, 256, 0, stream>>>(off, bsum);
  k_prep<<<(N_NODESC + 255) / 256, 256, 0, stream>>>(cnt, off, dinv, cursor);
  k_fill<<<(N_EDGESC + 255) / 256, 256, 0, stream>>>(ei, flag, cursor, csr);

  const int rpb = 98;
  const int gblk = (N_NODESC + rpb - 1) / rpb;  // 511 blocks
  const int ablk = (N_NODESC * 64 + 255) / 256; // 12500 blocks, 1 wave/node

  k_gemm<<<gblk, 256, 0, stream>>>(x, W1, T, rpb);
  k_agg<0><<<ablk, 256, 0, stream>>>(T, off, csr, dinv, b1, nullptr, nullptr, H);
  k_gemm<<<gblk, 256, 0, stream>>>(H, W2, T, rpb);
  k_agg<1><<<ablk, 256, 0, stream>>>(T, off, csr, dinv, b2, Wo, bo, out);
}

// Round 4
// 312.510 us; speedup vs baseline: 1.3753x; 1.3753x over previous
//
#include <hip/hip_runtime.h>
#include <math.h>

#define NN 50000
#define NE 800000

typedef __attribute__((ext_vector_type(8))) short bf16x8;
typedef __attribute__((ext_vector_type(4))) float f32x4;

__device__ __forceinline__ float b2f(unsigned short u) {
  union { unsigned u; float f; } v; v.u = ((unsigned)u) << 16; return v.f;
}
__device__ __forceinline__ unsigned short f2b(float f) {
  union { float f; unsigned u; } v; v.f = f;
  unsigned r = v.u + 0x7FFF + ((v.u >> 16) & 1);  // RNE
  return (unsigned short)(r >> 16);
}
// packed pair decode: word holds bf16 features (lo = 2*lane, hi = 2*lane+1)
__device__ __forceinline__ float plo(unsigned v) {
  union { unsigned u; float f; } t; t.u = v << 16; return t.f;
}
__device__ __forceinline__ float phi(unsigned v) {
  union { unsigned u; float f; } t; t.u = v & 0xFFFF0000u; return t.f;
}

// ---------------------------------------------------------------------------
// edge_index may arrive as int64 (reference dtype) or int32. flag=1 iff int64.
// ---------------------------------------------------------------------------
__device__ __forceinline__ int edge_val(const void* ei, long long idx, int is64) {
  if (is64) return (int)((const long long*)ei)[idx];
  return ((const int*)ei)[idx];
}

__global__ void k_detect(const unsigned int* __restrict__ ei, int* __restrict__ flag) {
  unsigned int v = ei[2 * threadIdx.x + 1];
  unsigned long long m = __ballot(v == 0u);
  if (threadIdx.x == 0) *flag = (m == ~0ull) ? 1 : 0;
}

__global__ void k_count(const void* __restrict__ ei, const int* __restrict__ flag,
                        int* __restrict__ cnt) {
  int e = blockIdx.x * blockDim.x + threadIdx.x;
  if (e >= NE) return;
  int is64 = *flag;
  int d = edge_val(ei, (long long)NE + e, is64);
  atomicAdd(&cnt[d], 1);
}

__global__ void k_scan1(const int* __restrict__ cnt, int* __restrict__ off,
                        int* __restrict__ bsum) {
  __shared__ int sh[1024];
  int i = blockIdx.x * 1024 + threadIdx.x;
  int v = (i < NN) ? cnt[i] : 0;
  sh[threadIdx.x] = v;
  __syncthreads();
  for (int s = 1; s < 1024; s <<= 1) {
    int t = (threadIdx.x >= s) ? sh[threadIdx.x - s] : 0;
    __syncthreads();
    sh[threadIdx.x] += t;
    __syncthreads();
  }
  if (i < NN) off[i + 1] = sh[threadIdx.x];
  if (threadIdx.x == 1023) bsum[blockIdx.x] = sh[1023];
}

__global__ void k_scan2(int* __restrict__ bsum, int nb) {
  int lane = threadIdx.x;
  int v = (lane < nb) ? bsum[lane] : 0;
  for (int s = 1; s < 64; s <<= 1) {
    int t = __shfl_up(v, s, 64);
    if (lane >= s) v += t;
  }
  if (lane < nb) bsum[lane] = v;
}

// finalize off, init cursor, compute dinv (merged old scan3 + prep)
__global__ void k_scan3p(int* __restrict__ off, const int* __restrict__ bsum,
                         const int* __restrict__ cnt, float* __restrict__ dinv,
                         int* __restrict__ cursor) {
  int i = blockIdx.x * blockDim.x + threadIdx.x;
  if (i >= NN) return;
  int b = i >> 10;
  int v = off[i + 1] + (b > 0 ? bsum[b - 1] : 0);
  off[i + 1] = v;
  cursor[i + 1] = v;
  if (i == 0) { off[0] = 0; cursor[0] = 0; }
  dinv[i] = rsqrtf((float)(cnt[i] + 1));
}

__global__ void k_fill(const void* __restrict__ ei, const int* __restrict__ flag,
                       int* __restrict__ cursor, int* __restrict__ csr) {
  int e = blockIdx.x * blockDim.x + threadIdx.x;
  if (e >= NE) return;
  int is64 = *flag;
  int d = edge_val(ei, (long long)NE + e, is64);
  int s = edge_val(ei, e, is64);
  int p = atomicAdd(&cursor[d], 1);
  csr[p] = s;
}

// transpose-cast W[k][n] f32 -> Wt[n][k] bf16  (128x128, one block)
__global__ void k_wt(const float* __restrict__ W, unsigned short* __restrict__ Wt) {
  for (int i = threadIdx.x; i < 128 * 128; i += 256) {
    int k = i >> 7, n = i & 127;
    Wt[n * 128 + k] = f2b(W[i]);
  }
}

// ---------------------------------------------------------------------------
// Out[M][128] bf16 = A[M][128] @ W  via MFMA 16x16x32 bf16.
// Wt[n][k] bf16. One wave per 16-row strip (grid-stride). B frags in regs.
// Layout (m89-verified): A row=lane&15,k=8*(lane>>4)+e; B col=lane&15 same k;
// D col=lane&15, row=4*(lane>>4)+reg.
// ---------------------------------------------------------------------------
template <int A_F32>
__global__ __launch_bounds__(256) void k_mgemm(const void* __restrict__ Ap,
                                               const unsigned short* __restrict__ Wt,
                                               unsigned short* __restrict__ Out,
                                               int M) {
  int wid  = (blockIdx.x * blockDim.x + threadIdx.x) >> 6;
  int lane = threadIdx.x & 63;
  int nw   = (gridDim.x * blockDim.x) >> 6;
  int r  = lane & 15;
  int kg = lane >> 4;
  bf16x8 bf[8][4];
#pragma unroll
  for (int n = 0; n < 8; ++n)
#pragma unroll
    for (int kk = 0; kk < 4; ++kk)
      bf[n][kk] = *(const bf16x8*)&Wt[(n * 16 + r) * 128 + kk * 32 + kg * 8];
  int nstr = M >> 4;  // M % 16 == 0 (50000 = 3125*16)
  for (int s = wid; s < nstr; s += nw) {
    int row = s * 16 + r;
    bf16x8 af[4];
    if (A_F32) {
      const float* Ar = (const float*)Ap + (long long)row * 128 + kg * 8;
#pragma unroll
      for (int kk = 0; kk < 4; ++kk) {
        float4 lo4 = *(const float4*)(Ar + kk * 32);
        float4 hi4 = *(const float4*)(Ar + kk * 32 + 4);
        bf16x8 t;
        t[0] = (short)f2b(lo4.x); t[1] = (short)f2b(lo4.y);
        t[2] = (short)f2b(lo4.z); t[3] = (short)f2b(lo4.w);
        t[4] = (short)f2b(hi4.x); t[5] = (short)f2b(hi4.y);
        t[6] = (short)f2b(hi4.z); t[7] = (short)f2b(hi4.w);
        af[kk] = t;
      }
    } else {
      const unsigned short* Ar = (const unsigned short*)Ap + (long long)row * 128 + kg * 8;
#pragma unroll
      for (int kk = 0; kk < 4; ++kk)
        af[kk] = *(const bf16x8*)(Ar + kk * 32);
    }
    f32x4 acc[8];
#pragma unroll
    for (int n = 0; n < 8; ++n) acc[n] = (f32x4){0.f, 0.f, 0.f, 0.f};
#pragma unroll
    for (int kk = 0; kk < 4; ++kk)
#pragma unroll
      for (int n = 0; n < 8; ++n)
        acc[n] = __builtin_amdgcn_mfma_f32_16x16x32_bf16(af[kk], bf[n][kk], acc[n], 0, 0, 0);
    int rowbase = s * 16 + kg * 4;
#pragma unroll
    for (int n = 0; n < 8; ++n)
#pragma unroll
      for (int j = 0; j < 4; ++j)
        Out[(long long)(rowbase + j) * 128 + n * 16 + r] = f2b(acc[n][j]);
  }
}

// ---------------------------------------------------------------------------
// Aggregation over bf16 rows: one wave per dst node (grid-stride), each lane
// owns packed feature pair (2*lane, 2*lane+1) = one dword per row access.
// out[d] = relu( dinv[d]*( sum_s dinv[s]*T[s] + dinv[d]*T[d] ) + b )
// FINAL=1 fuses 128->1 projection + sigmoid.
// ---------------------------------------------------------------------------
template <int FINAL>
__global__ __launch_bounds__(256) void k_agg(const unsigned short* __restrict__ Tb,
                                             const int* __restrict__ off,
                                             const int* __restrict__ csr,
                                             const float* __restrict__ dinv,
                                             const float* __restrict__ bias,
                                             const float* __restrict__ wout,
                                             const float* __restrict__ bout,
                                             void* __restrict__ outp) {
  const unsigned* Tw = (const unsigned*)Tb;  // 64 dwords per row
  int wid  = (blockIdx.x * blockDim.x + threadIdx.x) >> 6;
  int lane = threadIdx.x & 63;
  int nw   = (gridDim.x * blockDim.x) >> 6;
  float blo = bias[2 * lane], bhi = bias[2 * lane + 1];
  float wlo = 0.f, whi = 0.f;
  if (FINAL) { wlo = wout[2 * lane]; whi = wout[2 * lane + 1]; }
  for (int d = wid; d < NN; d += nw) {
    float dv = dinv[d];
    int e0 = off[d], e1 = off[d + 1];
    unsigned vs = Tw[d * 64 + lane];
    float a0 = dv * plo(vs);
    float a1 = dv * phi(vs);
    int e = e0;
    for (; e + 3 < e1; e += 4) {
      int s0 = csr[e], s1 = csr[e + 1], s2 = csr[e + 2], s3 = csr[e + 3];
      float w0 = dinv[s0], w1 = dinv[s1], w2 = dinv[s2], w3 = dinv[s3];
      unsigned v0 = Tw[s0 * 64 + lane];
      unsigned v1 = Tw[s1 * 64 + lane];
      unsigned v2 = Tw[s2 * 64 + lane];
      unsigned v3 = Tw[s3 * 64 + lane];
      a0 = fmaf(w0, plo(v0), a0); a1 = fmaf(w0, phi(v0), a1);
      a0 = fmaf(w1, plo(v1), a0); a1 = fmaf(w1, phi(v1), a1);
      a0 = fmaf(w2, plo(v2), a0); a1 = fmaf(w2, phi(v2), a1);
      a0 = fmaf(w3, plo(v3), a0); a1 = fmaf(w3, phi(v3), a1);
    }
    for (; e < e1; ++e) {
      int s = csr[e];
      float w = dinv[s];
      unsigned v = Tw[s * 64 + lane];
      a0 = fmaf(w, plo(v), a0);
      a1 = fmaf(w, phi(v), a1);
    }
    a0 = fmaxf(fmaf(a0, dv, blo), 0.f);
    a1 = fmaxf(fmaf(a1, dv, bhi), 0.f);
    if (FINAL) {
      float rsum = a0 * wlo + a1 * whi;
#pragma unroll
      for (int s2p = 32; s2p > 0; s2p >>= 1) rsum += __shfl_xor(rsum, s2p, 64);
      if (lane == 0) ((float*)outp)[d] = 1.f / (1.f + __expf(-(rsum + bout[0])));
    } else {
      unsigned o = (unsigned)f2b(a0) | ((unsigned)f2b(a1) << 16);
      ((unsigned*)outp)[d * 64 + lane] = o;
    }
  }
}

// ---------------------------------------------------------------------------
extern "C" void kernel_launch(void* const* d_in, const int* in_sizes, int n_in,
                              void* d_out, int out_size, void* d_ws, size_t ws_size,
                              hipStream_t stream) {
  const float* x  = (const float*)d_in[0];
  const void*  ei = d_in[1];
  const float* W1 = (const float*)d_in[2];
  const float* b1 = (const float*)d_in[3];
  const float* W2 = (const float*)d_in[4];
  const float* b2 = (const float*)d_in[5];
  const float* Wo = (const float*)d_in[6];
  const float* bo = (const float*)d_in[7];
  float* out = (float*)d_out;

  char* p = (char*)d_ws;
  auto alloc = [&](size_t bytes) {
    char* r = p;
    p += (bytes + 511) & ~(size_t)511;
    return r;
  };
  int*   flag   = (int*)alloc(sizeof(int));
  int*   cnt    = (int*)alloc(sizeof(int) * NN);
  int*   off    = (int*)alloc(sizeof(int) * (NN + 1));
  int*   cursor = (int*)alloc(sizeof(int) * (NN + 1));
  int*   bsum   = (int*)alloc(sizeof(int) * 64);
  float* dinv   = (float*)alloc(sizeof(float) * NN);
  int*   csr    = (int*)alloc(sizeof(int) * NE);
  unsigned short* Wt1 = (unsigned short*)alloc(sizeof(short) * 128 * 128);
  unsigned short* Wt2 = (unsigned short*)alloc(sizeof(short) * 128 * 128);
  unsigned short* T   = (unsigned short*)alloc(sizeof(short) * (size_t)NN * 128);
  unsigned short* H   = (unsigned short*)alloc(sizeof(short) * (size_t)NN * 128);

  hipMemsetAsync(cnt, 0, sizeof(int) * NN, stream);
  k_detect<<<1, 64, 0, stream>>>((const unsigned int*)ei, flag);
  k_count<<<(NE + 255) / 256, 256, 0, stream>>>(ei, flag, cnt);
  int nb = (NN + 1023) / 1024;  // 49
  k_scan1<<<nb, 1024, 0, stream>>>(cnt, off, bsum);
  k_scan2<<<1, 64, 0, stream>>>(bsum, nb);
  k_scan3p<<<(NN + 255) / 256, 256, 0, stream>>>(off, bsum, cnt, dinv, cursor);
  k_fill<<<(NE + 255) / 256, 256, 0, stream>>>(ei, flag, cursor, csr);
  k_wt<<<1, 256, 0, stream>>>(W1, Wt1);
  k_wt<<<1, 256, 0, stream>>>(W2, Wt2);

  k_mgemm<1><<<256, 256, 0, stream>>>(x, Wt1, T, NN);
  k_agg<0><<<2048, 256, 0, stream>>>(T, off, csr, dinv, b1, nullptr, nullptr, H);
  k_mgemm<0><<<256, 256, 0, stream>>>(H, Wt2, T, NN);
  k_agg<1><<<2048, 256, 0, stream>>>(T, off, csr, dinv, b2, Wo, bo, out);
}

// Round 5
// 286.676 us; speedup vs baseline: 1.4993x; 1.0901x over previous
//
#include <hip/hip_runtime.h>
#include <math.h>

#define NN 50000
#define NE 800000
#define NBUK 196          // ceil(50000/256), bucket = dst >> 8
#define PBLK 256          // partition blocks
#define EPB (NE / PBLK)   // 3125 edges per partition block

typedef __attribute__((ext_vector_type(8))) short bf16x8;
typedef __attribute__((ext_vector_type(4))) float f32x4;

__device__ __forceinline__ unsigned short f2b(float f) {
  union { float f; unsigned u; } v; v.f = f;
  unsigned r = v.u + 0x7FFF + ((v.u >> 16) & 1);  // RNE
  return (unsigned short)(r >> 16);
}
__device__ __forceinline__ float plo(unsigned v) {
  union { unsigned u; float f; } t; t.u = v << 16; return t.f;
}
__device__ __forceinline__ float phi(unsigned v) {
  union { unsigned u; float f; } t; t.u = v & 0xFFFF0000u; return t.f;
}

// ---------------------------------------------------------------------------
// edge_index may arrive as int64 (reference dtype) or int32. flag=1 iff int64.
// ---------------------------------------------------------------------------
__device__ __forceinline__ int edge_val(const void* ei, long long idx, int is64) {
  if (is64) return (int)((const long long*)ei)[idx];
  return ((const int*)ei)[idx];
}

__global__ void k_detect(const unsigned int* __restrict__ ei, int* __restrict__ flag) {
  unsigned int v = ei[2 * threadIdx.x + 1];
  unsigned long long m = __ballot(v == 0u);
  if (threadIdx.x == 0) *flag = (m == ~0ull) ? 1 : 0;
}

// ---- pass 1: per-block bucket histogram (LDS atomics only) ----------------
__global__ __launch_bounds__(256) void k_phist(const void* __restrict__ ei,
                                               const int* __restrict__ flag,
                                               int* __restrict__ bh) {
  __shared__ int hist[NBUK];
  if (threadIdx.x < NBUK) hist[threadIdx.x] = 0;
  __syncthreads();
  int is64 = *flag;
  int base = blockIdx.x * EPB;
  for (int e = base + threadIdx.x; e < base + EPB; e += 256) {
    int d = edge_val(ei, (long long)NE + e, is64);
    atomicAdd(&hist[d >> 8], 1);
  }
  __syncthreads();
  if (threadIdx.x < NBUK) bh[blockIdx.x * NBUK + threadIdx.x] = hist[threadIdx.x];
}

// ---- pass 2: in-place column scan of bh -> per-(block,bucket) offsets ------
// also writes bucketStart[0..NBUK] (global bucket bases).
__global__ __launch_bounds__(256) void k_pscan(int* __restrict__ bh,
                                               int* __restrict__ bstart) {
  __shared__ int sh[256];
  int k = threadIdx.x;
  int acc = 0;
  if (k < NBUK) {
    for (int b = 0; b < PBLK; ++b) {
      int t = bh[b * NBUK + k];
      bh[b * NBUK + k] = acc;
      acc += t;
    }
  }
  sh[k] = (k < NBUK) ? acc : 0;
  __syncthreads();
  // inclusive Hillis-Steele over 256
  for (int s = 1; s < 256; s <<= 1) {
    int t = (k >= s) ? sh[k - s] : 0;
    __syncthreads();
    sh[k] += t;
    __syncthreads();
  }
  int basek = (k == 0) ? 0 : sh[k - 1];
  if (k < NBUK) {
    bstart[k] = basek;
    for (int b = 0; b < PBLK; ++b) bh[b * NBUK + k] += basek;
  }
  if (k == 0) bstart[NBUK] = NE;
}

// ---- pass 3: scatter edges into bucket-partitioned (src,dst) arrays --------
__global__ __launch_bounds__(256) void k_pscat(const void* __restrict__ ei,
                                               const int* __restrict__ flag,
                                               const int* __restrict__ bh,
                                               int* __restrict__ esrc,
                                               int* __restrict__ edst) {
  __shared__ int cur[NBUK];
  if (threadIdx.x < NBUK) cur[threadIdx.x] = bh[blockIdx.x * NBUK + threadIdx.x];
  __syncthreads();
  int is64 = *flag;
  int base = blockIdx.x * EPB;
  for (int e = base + threadIdx.x; e < base + EPB; e += 256) {
    int d = edge_val(ei, (long long)NE + e, is64);
    int s = edge_val(ei, e, is64);
    int p = atomicAdd(&cur[d >> 8], 1);
    esrc[p] = s;
    edst[p] = d;
  }
}

// ---- pass 4: per-bucket node histogram -> cnt (coalesced, no atomics) ------
__global__ __launch_bounds__(256) void k_bcnt(const int* __restrict__ edst,
                                              const int* __restrict__ bstart,
                                              int* __restrict__ cnt) {
  __shared__ int hist[256];
  hist[threadIdx.x] = 0;
  __syncthreads();
  int k = blockIdx.x;
  int e0 = bstart[k], e1 = bstart[k + 1];
  for (int e = e0 + threadIdx.x; e < e1; e += 256)
    atomicAdd(&hist[edst[e] & 255], 1);
  __syncthreads();
  int node = k * 256 + threadIdx.x;
  if (node < NN) cnt[node] = hist[threadIdx.x];
}

// ---- node-level scans (unchanged machinery) --------------------------------
__global__ void k_scan1(const int* __restrict__ cnt, int* __restrict__ off,
                        int* __restrict__ bsum) {
  __shared__ int sh[1024];
  int i = blockIdx.x * 1024 + threadIdx.x;
  int v = (i < NN) ? cnt[i] : 0;
  sh[threadIdx.x] = v;
  __syncthreads();
  for (int s = 1; s < 1024; s <<= 1) {
    int t = (threadIdx.x >= s) ? sh[threadIdx.x - s] : 0;
    __syncthreads();
    sh[threadIdx.x] += t;
    __syncthreads();
  }
  if (i < NN) off[i + 1] = sh[threadIdx.x];
  if (threadIdx.x == 1023) bsum[blockIdx.x] = sh[1023];
}

__global__ void k_scan2(int* __restrict__ bsum, int nb) {
  int lane = threadIdx.x;
  int v = (lane < nb) ? bsum[lane] : 0;
  for (int s = 1; s < 64; s <<= 1) {
    int t = __shfl_up(v, s, 64);
    if (lane >= s) v += t;
  }
  if (lane < nb) bsum[lane] = v;
}

__global__ void k_scan3p(int* __restrict__ off, const int* __restrict__ bsum,
                         const int* __restrict__ cnt, float* __restrict__ dinv) {
  int i = blockIdx.x * blockDim.x + threadIdx.x;
  if (i >= NN) return;
  int b = i >> 10;
  int v = off[i + 1] + (b > 0 ? bsum[b - 1] : 0);
  off[i + 1] = v;
  if (i == 0) off[0] = 0;
  dinv[i] = rsqrtf((float)(cnt[i] + 1));
}

// ---- pass 5: per-bucket CSR fill (LDS cursors; bucket-local writes) --------
__global__ __launch_bounds__(256) void k_bfill(const int* __restrict__ esrc,
                                               const int* __restrict__ edst,
                                               const int* __restrict__ bstart,
                                               const int* __restrict__ off,
                                               int* __restrict__ csr) {
  __shared__ int cur[256];
  int k = blockIdx.x;
  int node = k * 256 + threadIdx.x;
  cur[threadIdx.x] = (node < NN) ? off[node] : 0;
  __syncthreads();
  int e0 = bstart[k], e1 = bstart[k + 1];
  for (int e = e0 + threadIdx.x; e < e1; e += 256) {
    int p = atomicAdd(&cur[edst[e] & 255], 1);
    csr[p] = esrc[e];
  }
}

// transpose-cast W[k][n] f32 -> Wt[n][k] bf16  (128x128, one block)
__global__ void k_wt(const float* __restrict__ W, unsigned short* __restrict__ Wt) {
  for (int i = threadIdx.x; i < 128 * 128; i += 256) {
    int k = i >> 7, n = i & 127;
    Wt[n * 128 + k] = f2b(W[i]);
  }
}

// ---------------------------------------------------------------------------
// Out[M][128] bf16 = A[M][128] @ W  via MFMA 16x16x32 bf16.
// Wt[n][k] bf16. One wave per 16-row strip (grid-stride). B frags in regs.
// Layout (m89-verified): A row=lane&15,k=8*(lane>>4)+e; B col=lane&15 same k;
// D col=lane&15, row=4*(lane>>4)+reg.
// ---------------------------------------------------------------------------
template <int A_F32>
__global__ __launch_bounds__(256) void k_mgemm(const void* __restrict__ Ap,
                                               const unsigned short* __restrict__ Wt,
                                               unsigned short* __restrict__ Out,
                                               int M) {
  int wid  = (blockIdx.x * blockDim.x + threadIdx.x) >> 6;
  int lane = threadIdx.x & 63;
  int nw   = (gridDim.x * blockDim.x) >> 6;
  int r  = lane & 15;
  int kg = lane >> 4;
  bf16x8 bf[8][4];
#pragma unroll
  for (int n = 0; n < 8; ++n)
#pragma unroll
    for (int kk = 0; kk < 4; ++kk)
      bf[n][kk] = *(const bf16x8*)&Wt[(n * 16 + r) * 128 + kk * 32 + kg * 8];
  int nstr = M >> 4;  // M % 16 == 0 (50000 = 3125*16)
  for (int s = wid; s < nstr; s += nw) {
    int row = s * 16 + r;
    bf16x8 af[4];
    if (A_F32) {
      const float* Ar = (const float*)Ap + (long long)row * 128 + kg * 8;
#pragma unroll
      for (int kk = 0; kk < 4; ++kk) {
        float4 lo4 = *(const float4*)(Ar + kk * 32);
        float4 hi4 = *(const float4*)(Ar + kk * 32 + 4);
        bf16x8 t;
        t[0] = (short)f2b(lo4.x); t[1] = (short)f2b(lo4.y);
        t[2] = (short)f2b(lo4.z); t[3] = (short)f2b(lo4.w);
        t[4] = (short)f2b(hi4.x); t[5] = (short)f2b(hi4.y);
        t[6] = (short)f2b(hi4.z); t[7] = (short)f2b(hi4.w);
        af[kk] = t;
      }
    } else {
      const unsigned short* Ar = (const unsigned short*)Ap + (long long)row * 128 + kg * 8;
#pragma unroll
      for (int kk = 0; kk < 4; ++kk)
        af[kk] = *(const bf16x8*)(Ar + kk * 32);
    }
    f32x4 acc[8];
#pragma unroll
    for (int n = 0; n < 8; ++n) acc[n] = (f32x4){0.f, 0.f, 0.f, 0.f};
#pragma unroll
    for (int kk = 0; kk < 4; ++kk)
#pragma unroll
      for (int n = 0; n < 8; ++n)
        acc[n] = __builtin_amdgcn_mfma_f32_16x16x32_bf16(af[kk], bf[n][kk], acc[n], 0, 0, 0);
    int rowbase = s * 16 + kg * 4;
#pragma unroll
    for (int n = 0; n < 8; ++n)
#pragma unroll
      for (int j = 0; j < 4; ++j)
        Out[(long long)(rowbase + j) * 128 + n * 16 + r] = f2b(acc[n][j]);
  }
}

// ---------------------------------------------------------------------------
// Aggregation over bf16 rows: one wave per dst node (grid-stride), each lane
// owns packed feature pair (2*lane, 2*lane+1) = one dword per row access.
// out[d] = relu( dinv[d]*( sum_s dinv[s]*T[s] + dinv[d]*T[d] ) + b )
// FINAL=1 fuses 128->1 projection + sigmoid.
// ---------------------------------------------------------------------------
template <int FINAL>
__global__ __launch_bounds__(256) void k_agg(const unsigned short* __restrict__ Tb,
                                             const int* __restrict__ off,
                                             const int* __restrict__ csr,
                                             const float* __restrict__ dinv,
                                             const float* __restrict__ bias,
                                             const float* __restrict__ wout,
                                             const float* __restrict__ bout,
                                             void* __restrict__ outp) {
  const unsigned* Tw = (const unsigned*)Tb;  // 64 dwords per row
  int wid  = (blockIdx.x * blockDim.x + threadIdx.x) >> 6;
  int lane = threadIdx.x & 63;
  int nw   = (gridDim.x * blockDim.x) >> 6;
  float blo = bias[2 * lane], bhi = bias[2 * lane + 1];
  float wlo = 0.f, whi = 0.f;
  if (FINAL) { wlo = wout[2 * lane]; whi = wout[2 * lane + 1]; }
  for (int d = wid; d < NN; d += nw) {
    float dv = dinv[d];
    int e0 = off[d], e1 = off[d + 1];
    unsigned vs = Tw[d * 64 + lane];
    float a0 = dv * plo(vs);
    float a1 = dv * phi(vs);
    int e = e0;
    for (; e + 3 < e1; e += 4) {
      int s0 = csr[e], s1 = csr[e + 1], s2 = csr[e + 2], s3 = csr[e + 3];
      float w0 = dinv[s0], w1 = dinv[s1], w2 = dinv[s2], w3 = dinv[s3];
      unsigned v0 = Tw[s0 * 64 + lane];
      unsigned v1 = Tw[s1 * 64 + lane];
      unsigned v2 = Tw[s2 * 64 + lane];
      unsigned v3 = Tw[s3 * 64 + lane];
      a0 = fmaf(w0, plo(v0), a0); a1 = fmaf(w0, phi(v0), a1);
      a0 = fmaf(w1, plo(v1), a0); a1 = fmaf(w1, phi(v1), a1);
      a0 = fmaf(w2, plo(v2), a0); a1 = fmaf(w2, phi(v2), a1);
      a0 = fmaf(w3, plo(v3), a0); a1 = fmaf(w3, phi(v3), a1);
    }
    for (; e < e1; ++e) {
      int s = csr[e];
      float w = dinv[s];
      unsigned v = Tw[s * 64 + lane];
      a0 = fmaf(w, plo(v), a0);
      a1 = fmaf(w, phi(v), a1);
    }
    a0 = fmaxf(fmaf(a0, dv, blo), 0.f);
    a1 = fmaxf(fmaf(a1, dv, bhi), 0.f);
    if (FINAL) {
      float rsum = a0 * wlo + a1 * whi;
#pragma unroll
      for (int s2p = 32; s2p > 0; s2p >>= 1) rsum += __shfl_xor(rsum, s2p, 64);
      if (lane == 0) ((float*)outp)[d] = 1.f / (1.f + __expf(-(rsum + bout[0])));
    } else {
      unsigned o = (unsigned)f2b(a0) | ((unsigned)f2b(a1) << 16);
      ((unsigned*)outp)[d * 64 + lane] = o;
    }
  }
}

// ---------------------------------------------------------------------------
extern "C" void kernel_launch(void* const* d_in, const int* in_sizes, int n_in,
                              void* d_out, int out_size, void* d_ws, size_t ws_size,
                              hipStream_t stream) {
  const float* x  = (const float*)d_in[0];
  const void*  ei = d_in[1];
  const float* W1 = (const float*)d_in[2];
  const float* b1 = (const float*)d_in[3];
  const float* W2 = (const float*)d_in[4];
  const float* b2 = (const float*)d_in[5];
  const float* Wo = (const float*)d_in[6];
  const float* bo = (const float*)d_in[7];
  float* out = (float*)d_out;

  char* p = (char*)d_ws;
  auto alloc = [&](size_t bytes) {
    char* r = p;
    p += (bytes + 511) & ~(size_t)511;
    return r;
  };
  int*   flag   = (int*)alloc(sizeof(int));
  int*   cnt    = (int*)alloc(sizeof(int) * NN);
  int*   off    = (int*)alloc(sizeof(int) * (NN + 1));
  int*   bsum   = (int*)alloc(sizeof(int) * 64);
  float* dinv   = (float*)alloc(sizeof(float) * NN);
  int*   bh     = (int*)alloc(sizeof(int) * PBLK * NBUK);
  int*   bstart = (int*)alloc(sizeof(int) * (NBUK + 1));
  int*   csr    = (int*)alloc(sizeof(int) * NE);
  unsigned short* Wt1 = (unsigned short*)alloc(sizeof(short) * 128 * 128);
  unsigned short* Wt2 = (unsigned short*)alloc(sizeof(short) * 128 * 128);
  unsigned short* T   = (unsigned short*)alloc(sizeof(short) * (size_t)NN * 128);
  unsigned short* H   = (unsigned short*)alloc(sizeof(short) * (size_t)NN * 128);
  // partition pair buffers alias T (dead before first k_mgemm writes T)
  int* esrc = (int*)T;
  int* edst = esrc + NE;   // 6.4 MB total <= T's 12.8 MB

  k_detect<<<1, 64, 0, stream>>>((const unsigned int*)ei, flag);
  k_phist<<<PBLK, 256, 0, stream>>>(ei, flag, bh);
  k_pscan<<<1, 256, 0, stream>>>(bh, bstart);
  k_pscat<<<PBLK, 256, 0, stream>>>(ei, flag, bh, esrc, edst);
  k_bcnt<<<NBUK, 256, 0, stream>>>(edst, bstart, cnt);
  int nb = (NN + 1023) / 1024;  // 49
  k_scan1<<<nb, 1024, 0, stream>>>(cnt, off, bsum);
  k_scan2<<<1, 64, 0, stream>>>(bsum, nb);
  k_scan3p<<<(NN + 255) / 256, 256, 0, stream>>>(off, bsum, cnt, dinv);
  k_bfill<<<NBUK, 256, 0, stream>>>(esrc, edst, bstart, off, csr);
  k_wt<<<1, 256, 0, stream>>>(W1, Wt1);
  k_wt<<<1, 256, 0, stream>>>(W2, Wt2);

  k_mgemm<1><<<256, 256, 0, stream>>>(x, Wt1, T, NN);
  k_agg<0><<<2048, 256, 0, stream>>>(T, off, csr, dinv, b1, nullptr, nullptr, H);
  k_mgemm<0><<<256, 256, 0, stream>>>(H, Wt2, T, NN);
  k_agg<1><<<2048, 256, 0, stream>>>(T, off, csr, dinv, b2, Wo, bo, out);
}

// Round 6
// 241.696 us; speedup vs baseline: 1.7783x; 1.1861x over previous
//
#include <hip/hip_runtime.h>
#include <math.h>

#define NN 50000
#define NE 800000
#define NBUK 196          // ceil(50000/256), bucket = dst >> 8
#define PBLK 256          // partition blocks
#define EPB (NE / PBLK)   // 3125 edges per partition block

typedef __attribute__((ext_vector_type(8))) short bf16x8;
typedef __attribute__((ext_vector_type(4))) float f32x4;

__device__ __forceinline__ unsigned short f2b(float f) {
  union { float f; unsigned u; } v; v.f = f;
  unsigned r = v.u + 0x7FFF + ((v.u >> 16) & 1);  // RNE
  return (unsigned short)(r >> 16);
}
__device__ __forceinline__ float plo(unsigned v) {
  union { unsigned u; float f; } t; t.u = v << 16; return t.f;
}
__device__ __forceinline__ float phi(unsigned v) {
  union { unsigned u; float f; } t; t.u = v & 0xFFFF0000u; return t.f;
}

__device__ __forceinline__ int edge_val(const void* ei, long long idx, int is64) {
  if (is64) return (int)((const long long*)ei)[idx];
  return ((const int*)ei)[idx];
}

// ---- pass 1: per-block bucket histogram; bh bucket-major [NBUK][PBLK] ------
__global__ __launch_bounds__(256) void k_phist(const void* __restrict__ ei,
                                               int* __restrict__ bh) {
  __shared__ int hist[NBUK];
  __shared__ int sflag;
  if (threadIdx.x < 64) {  // inline int64-vs-int32 detect (wave 0)
    unsigned v = ((const unsigned*)ei)[2 * threadIdx.x + 1];
    unsigned long long m = __ballot(v == 0u);
    if (threadIdx.x == 0) sflag = (m == ~0ull) ? 1 : 0;
  }
  if (threadIdx.x < NBUK) hist[threadIdx.x] = 0;
  __syncthreads();
  int is64 = sflag;
  int base = blockIdx.x * EPB;
  for (int e = base + threadIdx.x; e < base + EPB; e += 256) {
    int d = edge_val(ei, (long long)NE + e, is64);
    atomicAdd(&hist[d >> 8], 1);
  }
  __syncthreads();
  if (threadIdx.x < NBUK) bh[threadIdx.x * PBLK + blockIdx.x] = hist[threadIdx.x];
}

// ---- pass 2a: per-bucket exclusive scan over the 256 block-counts ----------
__global__ __launch_bounds__(256) void k_pscanA(int* __restrict__ bh,
                                                int* __restrict__ colsum) {
  __shared__ int sh[256];
  int k = blockIdx.x, t = threadIdx.x;
  int v = bh[k * PBLK + t];
  sh[t] = v;
  __syncthreads();
  for (int s = 1; s < 256; s <<= 1) {
    int u = (t >= s) ? sh[t - s] : 0;
    __syncthreads();
    sh[t] += u;
    __syncthreads();
  }
  bh[k * PBLK + t] = sh[t] - v;  // exclusive
  if (t == 255) colsum[k] = sh[255];
}

// ---- pass 2b: scan bucket totals -> bstart ---------------------------------
__global__ __launch_bounds__(256) void k_pscanB(const int* __restrict__ colsum,
                                                int* __restrict__ bstart) {
  __shared__ int sh[256];
  int t = threadIdx.x;
  sh[t] = (t < NBUK) ? colsum[t] : 0;
  __syncthreads();
  for (int s = 1; s < 256; s <<= 1) {
    int u = (t >= s) ? sh[t - s] : 0;
    __syncthreads();
    sh[t] += u;
    __syncthreads();
  }
  if (t <= NBUK) bstart[t] = (t == 0) ? 0 : sh[t - 1];
}

// ---- pass 3: scatter edges into bucket-partitioned (src,dst) pairs ---------
__global__ __launch_bounds__(256) void k_pscat(const void* __restrict__ ei,
                                               const int* __restrict__ bh,
                                               const int* __restrict__ bstart,
                                               int2* __restrict__ epair) {
  __shared__ int cur[NBUK];
  __shared__ int sflag;
  if (threadIdx.x < 64) {
    unsigned v = ((const unsigned*)ei)[2 * threadIdx.x + 1];
    unsigned long long m = __ballot(v == 0u);
    if (threadIdx.x == 0) sflag = (m == ~0ull) ? 1 : 0;
  }
  if (threadIdx.x < NBUK)
    cur[threadIdx.x] = bstart[threadIdx.x] + bh[threadIdx.x * PBLK + blockIdx.x];
  __syncthreads();
  int is64 = sflag;
  int base = blockIdx.x * EPB;
  for (int e = base + threadIdx.x; e < base + EPB; e += 256) {
    int d = edge_val(ei, (long long)NE + e, is64);
    int s = edge_val(ei, e, is64);
    int p = atomicAdd(&cur[d >> 8], 1);
    epair[p] = make_int2(s, d);
  }
}

// ---- pass 4: per-bucket count + LDS scan -> off, dinv (replaces 4 kernels) -
__global__ __launch_bounds__(256) void k_boff(const int2* __restrict__ epair,
                                              const int* __restrict__ bstart,
                                              int* __restrict__ off,
                                              float* __restrict__ dinv) {
  __shared__ int hist[256];
  int k = blockIdx.x, t = threadIdx.x;
  hist[t] = 0;
  __syncthreads();
  int e0 = bstart[k], e1 = bstart[k + 1];
  for (int e = e0 + t; e < e1; e += 256)
    atomicAdd(&hist[epair[e].y & 255], 1);
  __syncthreads();
  int myc = hist[t];
  for (int s = 1; s < 256; s <<= 1) {
    int u = (t >= s) ? hist[t - s] : 0;
    __syncthreads();
    hist[t] += u;
    __syncthreads();
  }
  int node = k * 256 + t;
  if (node < NN) {
    off[node] = e0 + hist[t] - myc;        // exclusive in-bucket prefix
    dinv[node] = rsqrtf((float)(myc + 1)); // +1 self loop
  }
  if (k == 0 && t == 0) off[NN] = NE;
}

// ---- pass 5: per-bucket CSR fill (LDS cursors; bucket-local writes) --------
__global__ __launch_bounds__(256) void k_bfill(const int2* __restrict__ epair,
                                               const int* __restrict__ bstart,
                                               const int* __restrict__ off,
                                               int* __restrict__ csr) {
  __shared__ int cur[256];
  int k = blockIdx.x, t = threadIdx.x;
  int node = k * 256 + t;
  cur[t] = (node < NN) ? off[node] : 0;
  __syncthreads();
  int e0 = bstart[k], e1 = bstart[k + 1];
  for (int e = e0 + t; e < e1; e += 256) {
    int2 p2 = epair[e];
    int p = atomicAdd(&cur[p2.y & 255], 1);
    csr[p] = p2.x;
  }
}

// transpose-cast both weights W[k][n] f32 -> Wt[n][k] bf16 (parallel) --------
__global__ __launch_bounds__(256) void k_wt2(const float* __restrict__ W1,
                                             const float* __restrict__ W2,
                                             unsigned short* __restrict__ Wt1,
                                             unsigned short* __restrict__ Wt2) {
  int i = blockIdx.x * 256 + threadIdx.x;   // 0..32767
  int sel = i >> 14;
  int j = i & 16383;
  int k = j >> 7, n = j & 127;
  const float* W = sel ? W2 : W1;
  unsigned short* Wt = sel ? Wt2 : Wt1;
  Wt[n * 128 + k] = f2b(W[j]);
}

// ---------------------------------------------------------------------------
// Out[M][128] bf16 = A[M][128] @ W via MFMA 16x16x32 bf16, SWAPPED operands:
//   A-operand = Wt rows (features), B-operand = input rows.
//   D: col=lane&15 -> input row in strip; row=4*(lane>>4)+reg -> feature.
// Each lane thus holds 4 CONSECUTIVE features -> packed uint2 stores.
// ---------------------------------------------------------------------------
template <int A_F32>
__global__ __launch_bounds__(256, 2) void k_mgemm(const void* __restrict__ Ap,
                                                  const unsigned short* __restrict__ Wt,
                                                  unsigned short* __restrict__ Out,
                                                  int M) {
  int wid  = (blockIdx.x * blockDim.x + threadIdx.x) >> 6;
  int lane = threadIdx.x & 63;
  int nw   = (gridDim.x * blockDim.x) >> 6;
  int r  = lane & 15;
  int kg = lane >> 4;
  bf16x8 wf[8][4];
#pragma unroll
  for (int n = 0; n < 8; ++n)
#pragma unroll
    for (int kk = 0; kk < 4; ++kk)
      wf[n][kk] = *(const bf16x8*)&Wt[(n * 16 + r) * 128 + kk * 32 + kg * 8];
  int nstr = M >> 4;  // 50000 = 3125*16
  for (int s = wid; s < nstr; s += nw) {
    int row = s * 16 + r;
    bf16x8 xf[4];
    if (A_F32) {
      const float* Ar = (const float*)Ap + (long long)row * 128 + kg * 8;
#pragma unroll
      for (int kk = 0; kk < 4; ++kk) {
        float4 lo4 = *(const float4*)(Ar + kk * 32);
        float4 hi4 = *(const float4*)(Ar + kk * 32 + 4);
        bf16x8 t;
        t[0] = (short)f2b(lo4.x); t[1] = (short)f2b(lo4.y);
        t[2] = (short)f2b(lo4.z); t[3] = (short)f2b(lo4.w);
        t[4] = (short)f2b(hi4.x); t[5] = (short)f2b(hi4.y);
        t[6] = (short)f2b(hi4.z); t[7] = (short)f2b(hi4.w);
        xf[kk] = t;
      }
    } else {
      const unsigned short* Ar = (const unsigned short*)Ap + (long long)row * 128 + kg * 8;
#pragma unroll
      for (int kk = 0; kk < 4; ++kk)
        xf[kk] = *(const bf16x8*)(Ar + kk * 32);
    }
    f32x4 acc[8];
#pragma unroll
    for (int n = 0; n < 8; ++n) acc[n] = (f32x4){0.f, 0.f, 0.f, 0.f};
#pragma unroll
    for (int kk = 0; kk < 4; ++kk)
#pragma unroll
      for (int n = 0; n < 8; ++n)
        acc[n] = __builtin_amdgcn_mfma_f32_16x16x32_bf16(wf[n][kk], xf[kk], acc[n], 0, 0, 0);
    // lane writes features n*16 + kg*4 + {0..3} of row `row` as one uint2
    unsigned short* Or = Out + (long long)row * 128 + kg * 4;
#pragma unroll
    for (int n = 0; n < 8; ++n) {
      uint2 o;
      o.x = (unsigned)f2b(acc[n][0]) | ((unsigned)f2b(acc[n][1]) << 16);
      o.y = (unsigned)f2b(acc[n][2]) | ((unsigned)f2b(acc[n][3]) << 16);
      *(uint2*)(Or + n * 16) = o;
    }
  }
}

// ---------------------------------------------------------------------------
// Aggregation over bf16 rows: one wave per dst node (grid-stride), each lane
// owns packed feature pair (2*lane, 2*lane+1) = one dword per row access.
// out[d] = relu( dinv[d]*( sum_s dinv[s]*T[s] + dinv[d]*T[d] ) + b )
// FINAL=1 fuses 128->1 projection + sigmoid. Edge loop unrolled x8.
// ---------------------------------------------------------------------------
template <int FINAL>
__global__ __launch_bounds__(256) void k_agg(const unsigned short* __restrict__ Tb,
                                             const int* __restrict__ off,
                                             const int* __restrict__ csr,
                                             const float* __restrict__ dinv,
                                             const float* __restrict__ bias,
                                             const float* __restrict__ wout,
                                             const float* __restrict__ bout,
                                             void* __restrict__ outp) {
  const unsigned* Tw = (const unsigned*)Tb;  // 64 dwords per row
  int wid  = (blockIdx.x * blockDim.x + threadIdx.x) >> 6;
  int lane = threadIdx.x & 63;
  int nw   = (gridDim.x * blockDim.x) >> 6;
  float blo = bias[2 * lane], bhi = bias[2 * lane + 1];
  float wlo = 0.f, whi = 0.f;
  if (FINAL) { wlo = wout[2 * lane]; whi = wout[2 * lane + 1]; }
  for (int d = wid; d < NN; d += nw) {
    float dv = dinv[d];
    int e0 = off[d], e1 = off[d + 1];
    unsigned vs = Tw[d * 64 + lane];
    float a0 = dv * plo(vs);
    float a1 = dv * phi(vs);
    int e = e0;
    int e8 = e0 + ((e1 - e0) & ~7);
    for (; e < e8; e += 8) {
      int   si[8]; float wi[8]; unsigned vi[8];
#pragma unroll
      for (int q = 0; q < 8; ++q) si[q] = csr[e + q];
#pragma unroll
      for (int q = 0; q < 8; ++q) wi[q] = dinv[si[q]];
#pragma unroll
      for (int q = 0; q < 8; ++q) vi[q] = Tw[si[q] * 64 + lane];
#pragma unroll
      for (int q = 0; q < 8; ++q) {
        a0 = fmaf(wi[q], plo(vi[q]), a0);
        a1 = fmaf(wi[q], phi(vi[q]), a1);
      }
    }
    for (; e < e1; ++e) {
      int s = csr[e];
      float w = dinv[s];
      unsigned v = Tw[s * 64 + lane];
      a0 = fmaf(w, plo(v), a0);
      a1 = fmaf(w, phi(v), a1);
    }
    a0 = fmaxf(fmaf(a0, dv, blo), 0.f);
    a1 = fmaxf(fmaf(a1, dv, bhi), 0.f);
    if (FINAL) {
      float rsum = a0 * wlo + a1 * whi;
#pragma unroll
      for (int s2p = 32; s2p > 0; s2p >>= 1) rsum += __shfl_xor(rsum, s2p, 64);
      if (lane == 0) ((float*)outp)[d] = 1.f / (1.f + __expf(-(rsum + bout[0])));
    } else {
      unsigned o = (unsigned)f2b(a0) | ((unsigned)f2b(a1) << 16);
      ((unsigned*)outp)[d * 64 + lane] = o;
    }
  }
}

// ---------------------------------------------------------------------------
extern "C" void kernel_launch(void* const* d_in, const int* in_sizes, int n_in,
                              void* d_out, int out_size, void* d_ws, size_t ws_size,
                              hipStream_t stream) {
  const float* x  = (const float*)d_in[0];
  const void*  ei = d_in[1];
  const float* W1 = (const float*)d_in[2];
  const float* b1 = (const float*)d_in[3];
  const float* W2 = (const float*)d_in[4];
  const float* b2 = (const float*)d_in[5];
  const float* Wo = (const float*)d_in[6];
  const float* bo = (const float*)d_in[7];
  float* out = (float*)d_out;

  char* p = (char*)d_ws;
  auto alloc = [&](size_t bytes) {
    char* r = p;
    p += (bytes + 511) & ~(size_t)511;
    return r;
  };
  int*   bh     = (int*)alloc(sizeof(int) * NBUK * PBLK);
  int*   colsum = (int*)alloc(sizeof(int) * NBUK);
  int*   bstart = (int*)alloc(sizeof(int) * (NBUK + 1));
  int*   off    = (int*)alloc(sizeof(int) * (NN + 1));
  float* dinv   = (float*)alloc(sizeof(float) * NN);
  int*   csr    = (int*)alloc(sizeof(int) * NE);
  unsigned short* Wt1 = (unsigned short*)alloc(sizeof(short) * 128 * 128);
  unsigned short* Wt2 = (unsigned short*)alloc(sizeof(short) * 128 * 128);
  unsigned short* T   = (unsigned short*)alloc(sizeof(short) * (size_t)NN * 128);
  unsigned short* H   = (unsigned short*)alloc(sizeof(short) * (size_t)NN * 128);
  int2* epair = (int2*)T;  // 6.4 MB, dead before k_mgemm<1> writes T

  k_phist<<<PBLK, 256, 0, stream>>>(ei, bh);
  k_pscanA<<<NBUK, 256, 0, stream>>>(bh, colsum);
  k_pscanB<<<1, 256, 0, stream>>>(colsum, bstart);
  k_pscat<<<PBLK, 256, 0, stream>>>(ei, bh, bstart, epair);
  k_boff<<<NBUK, 256, 0, stream>>>(epair, bstart, off, dinv);
  k_bfill<<<NBUK, 256, 0, stream>>>(epair, bstart, off, csr);
  k_wt2<<<128, 256, 0, stream>>>(W1, W2, Wt1, Wt2);

  k_mgemm<1><<<512, 256, 0, stream>>>(x, Wt1, T, NN);
  k_agg<0><<<2048, 256, 0, stream>>>(T, off, csr, dinv, b1, nullptr, nullptr, H);
  k_mgemm<0><<<512, 256, 0, stream>>>(H, Wt2, T, NN);
  k_agg<1><<<2048, 256, 0, stream>>>(T, off, csr, dinv, b2, Wo, bo, out);
}

// Round 7
// 212.266 us; speedup vs baseline: 2.0249x; 1.1386x over previous
//
#include <hip/hip_runtime.h>
#include <math.h>

#define NN 50000
#define NE 800000
#define NBUK 196          // ceil(50000/256), bucket = dst >> 8
#define PBLK 256          // partition blocks
#define EPB (NE / PBLK)   // 3125 edges per partition block

typedef __attribute__((ext_vector_type(8))) short bf16x8;
typedef __attribute__((ext_vector_type(4))) float f32x4;

__device__ __forceinline__ unsigned short f2b(float f) {
  union { float f; unsigned u; } v; v.f = f;
  unsigned r = v.u + 0x7FFF + ((v.u >> 16) & 1);  // RNE
  return (unsigned short)(r >> 16);
}
__device__ __forceinline__ float plo(unsigned v) {
  union { unsigned u; float f; } t; t.u = v << 16; return t.f;
}
__device__ __forceinline__ float phi(unsigned v) {
  union { unsigned u; float f; } t; t.u = v & 0xFFFF0000u; return t.f;
}

__device__ __forceinline__ int edge_val(const void* ei, long long idx, int is64) {
  if (is64) return (int)((const long long*)ei)[idx];
  return ((const int*)ei)[idx];
}

// ---- pass 1: per-block bucket histogram; bh bucket-major [NBUK][PBLK] ------
__global__ __launch_bounds__(256) void k_phist(const void* __restrict__ ei,
                                               int* __restrict__ bh) {
  __shared__ int hist[NBUK];
  __shared__ int sflag;
  if (threadIdx.x < 64) {  // inline int64-vs-int32 detect (wave 0)
    unsigned v = ((const unsigned*)ei)[2 * threadIdx.x + 1];
    unsigned long long m = __ballot(v == 0u);
    if (threadIdx.x == 0) sflag = (m == ~0ull) ? 1 : 0;
  }
  if (threadIdx.x < NBUK) hist[threadIdx.x] = 0;
  __syncthreads();
  int is64 = sflag;
  int base = blockIdx.x * EPB;
  for (int e = base + threadIdx.x; e < base + EPB; e += 256) {
    int d = edge_val(ei, (long long)NE + e, is64);
    atomicAdd(&hist[d >> 8], 1);
  }
  __syncthreads();
  if (threadIdx.x < NBUK) bh[threadIdx.x * PBLK + blockIdx.x] = hist[threadIdx.x];
}

// ---- pass 2a: per-bucket exclusive scan over the 256 block-counts ----------
__global__ __launch_bounds__(256) void k_pscanA(int* __restrict__ bh,
                                                int* __restrict__ colsum) {
  __shared__ int sh[256];
  int k = blockIdx.x, t = threadIdx.x;
  int v = bh[k * PBLK + t];
  sh[t] = v;
  __syncthreads();
  for (int s = 1; s < 256; s <<= 1) {
    int u = (t >= s) ? sh[t - s] : 0;
    __syncthreads();
    sh[t] += u;
    __syncthreads();
  }
  bh[k * PBLK + t] = sh[t] - v;  // exclusive
  if (t == 255) colsum[k] = sh[255];
}

// ---- pass 2b: scan bucket totals -> bstart ---------------------------------
__global__ __launch_bounds__(256) void k_pscanB(const int* __restrict__ colsum,
                                                int* __restrict__ bstart) {
  __shared__ int sh[256];
  int t = threadIdx.x;
  sh[t] = (t < NBUK) ? colsum[t] : 0;
  __syncthreads();
  for (int s = 1; s < 256; s <<= 1) {
    int u = (t >= s) ? sh[t - s] : 0;
    __syncthreads();
    sh[t] += u;
    __syncthreads();
  }
  if (t <= NBUK) bstart[t] = (t == 0) ? 0 : sh[t - 1];
}

// ---- pass 3: scatter edges into bucket-partitioned packed words ------------
// epk = src (16b) | dst-in-bucket (8b) << 16      (NN < 65536)
__global__ __launch_bounds__(256) void k_pscat(const void* __restrict__ ei,
                                               const int* __restrict__ bh,
                                               const int* __restrict__ bstart,
                                               unsigned* __restrict__ epk) {
  __shared__ int cur[NBUK];
  __shared__ int sflag;
  if (threadIdx.x < 64) {
    unsigned v = ((const unsigned*)ei)[2 * threadIdx.x + 1];
    unsigned long long m = __ballot(v == 0u);
    if (threadIdx.x == 0) sflag = (m == ~0ull) ? 1 : 0;
  }
  if (threadIdx.x < NBUK)
    cur[threadIdx.x] = bstart[threadIdx.x] + bh[threadIdx.x * PBLK + blockIdx.x];
  __syncthreads();
  int is64 = sflag;
  int base = blockIdx.x * EPB;
  for (int e = base + threadIdx.x; e < base + EPB; e += 256) {
    int d = edge_val(ei, (long long)NE + e, is64);
    int s = edge_val(ei, e, is64);
    int p = atomicAdd(&cur[d >> 8], 1);
    epk[p] = (unsigned)s | ((unsigned)(d & 255) << 16);
  }
}

// ---- pass 4: per-bucket hist+scan -> off,dinv, then CSR16 fill (merged) ----
__global__ __launch_bounds__(256) void k_bofffill(const unsigned* __restrict__ epk,
                                                  const int* __restrict__ bstart,
                                                  int* __restrict__ off,
                                                  float* __restrict__ dinv,
                                                  unsigned short* __restrict__ csr16) {
  __shared__ int hist[256];
  __shared__ int cur[256];
  int k = blockIdx.x, t = threadIdx.x;
  hist[t] = 0;
  __syncthreads();
  int e0 = bstart[k], e1 = bstart[k + 1];
  for (int e = e0 + t; e < e1; e += 256)
    atomicAdd(&hist[(epk[e] >> 16) & 255], 1);
  __syncthreads();
  int myc = hist[t];
  for (int s = 1; s < 256; s <<= 1) {
    int u = (t >= s) ? hist[t - s] : 0;
    __syncthreads();
    hist[t] += u;
    __syncthreads();
  }
  int excl = hist[t] - myc;  // exclusive in-bucket prefix
  int node = k * 256 + t;
  if (node < NN) {
    off[node] = e0 + excl;
    dinv[node] = rsqrtf((float)(myc + 1));  // +1 self loop
  }
  cur[t] = e0 + excl;
  __syncthreads();
  for (int e = e0 + t; e < e1; e += 256) {
    unsigned pk = epk[e];
    int p = atomicAdd(&cur[(pk >> 16) & 255], 1);
    csr16[p] = (unsigned short)(pk & 0xFFFFu);
  }
  if (k == 0 && t == 0) off[NN] = NE;
}

// transpose-cast both weights W[k][n] f32 -> Wt[n][k] bf16 (parallel) --------
__global__ __launch_bounds__(256) void k_wt2(const float* __restrict__ W1,
                                             const float* __restrict__ W2,
                                             unsigned short* __restrict__ Wt1,
                                             unsigned short* __restrict__ Wt2) {
  int i = blockIdx.x * 256 + threadIdx.x;   // 0..32767
  int sel = i >> 14;
  int j = i & 16383;
  int k = j >> 7, n = j & 127;
  const float* W = sel ? W2 : W1;
  unsigned short* Wt = sel ? Wt2 : Wt1;
  Wt[n * 128 + k] = f2b(W[j]);
}

// ---------------------------------------------------------------------------
// Out[M][128] bf16 = dinv[row] * (A[M][128] @ W) via MFMA, swapped operands.
// D: col=lane&15 -> row in strip; row=4*(lane>>4)+reg -> feature (packed st).
// ---------------------------------------------------------------------------
template <int A_F32>
__global__ __launch_bounds__(256, 2) void k_mgemm(const void* __restrict__ Ap,
                                                  const unsigned short* __restrict__ Wt,
                                                  const float* __restrict__ dinv,
                                                  unsigned short* __restrict__ Out,
                                                  int M) {
  int wid  = (blockIdx.x * blockDim.x + threadIdx.x) >> 6;
  int lane = threadIdx.x & 63;
  int nw   = (gridDim.x * blockDim.x) >> 6;
  int r  = lane & 15;
  int kg = lane >> 4;
  bf16x8 wf[8][4];
#pragma unroll
  for (int n = 0; n < 8; ++n)
#pragma unroll
    for (int kk = 0; kk < 4; ++kk)
      wf[n][kk] = *(const bf16x8*)&Wt[(n * 16 + r) * 128 + kk * 32 + kg * 8];
  int nstr = M >> 4;  // 50000 = 3125*16
  for (int s = wid; s < nstr; s += nw) {
    int row = s * 16 + r;
    bf16x8 xf[4];
    if (A_F32) {
      const float* Ar = (const float*)Ap + (long long)row * 128 + kg * 8;
#pragma unroll
      for (int kk = 0; kk < 4; ++kk) {
        float4 lo4 = *(const float4*)(Ar + kk * 32);
        float4 hi4 = *(const float4*)(Ar + kk * 32 + 4);
        bf16x8 t;
        t[0] = (short)f2b(lo4.x); t[1] = (short)f2b(lo4.y);
        t[2] = (short)f2b(lo4.z); t[3] = (short)f2b(lo4.w);
        t[4] = (short)f2b(hi4.x); t[5] = (short)f2b(hi4.y);
        t[6] = (short)f2b(hi4.z); t[7] = (short)f2b(hi4.w);
        xf[kk] = t;
      }
    } else {
      const unsigned short* Ar = (const unsigned short*)Ap + (long long)row * 128 + kg * 8;
#pragma unroll
      for (int kk = 0; kk < 4; ++kk)
        xf[kk] = *(const bf16x8*)(Ar + kk * 32);
    }
    f32x4 acc[8];
#pragma unroll
    for (int n = 0; n < 8; ++n) acc[n] = (f32x4){0.f, 0.f, 0.f, 0.f};
#pragma unroll
    for (int kk = 0; kk < 4; ++kk)
#pragma unroll
      for (int n = 0; n < 8; ++n)
        acc[n] = __builtin_amdgcn_mfma_f32_16x16x32_bf16(wf[n][kk], xf[kk], acc[n], 0, 0, 0);
    float dv = dinv[row];
    unsigned short* Or = Out + (long long)row * 128 + kg * 4;
#pragma unroll
    for (int n = 0; n < 8; ++n) {
      uint2 o;
      o.x = (unsigned)f2b(acc[n][0] * dv) | ((unsigned)f2b(acc[n][1] * dv) << 16);
      o.y = (unsigned)f2b(acc[n][2] * dv) | ((unsigned)f2b(acc[n][3] * dv) << 16);
      *(uint2*)(Or + n * 16) = o;
    }
  }
}

// ---------------------------------------------------------------------------
// Aggregation over PRE-SCALED bf16 rows: one wave per dst node; half-wave
// pairing: lanes 0-31 process even edges, 32-63 odd edges; each lane loads
// uint2 (4 features). out[d] = relu( dinv[d]*(sum Ts[s] + Ts[d]) + b ).
// Init step: half 0 loads self row, half 1 loads the odd tail edge (if any).
// FINAL=1 fuses 128->1 projection + sigmoid.
// ---------------------------------------------------------------------------
template <int FINAL>
__global__ __launch_bounds__(256) void k_agg(const unsigned short* __restrict__ Tb,
                                             const int* __restrict__ off,
                                             const unsigned short* __restrict__ csr16,
                                             const float* __restrict__ dinv,
                                             const float* __restrict__ bias,
                                             const float* __restrict__ wout,
                                             const float* __restrict__ bout,
                                             void* __restrict__ outp) {
  const uint2* Tw2 = (const uint2*)Tb;  // 32 uint2 per 128-feature row
  int wid  = (blockIdx.x * blockDim.x + threadIdx.x) >> 6;
  int lane = threadIdx.x & 63;
  int half = lane >> 5;
  int li   = lane & 31;
  int nw   = (gridDim.x * blockDim.x) >> 6;
  float4 b4 = ((const float4*)bias)[li];
  float4 w4 = make_float4(0.f, 0.f, 0.f, 0.f);
  if (FINAL) w4 = ((const float4*)wout)[li];
  for (int d = wid; d < NN; d += nw) {
    int e0 = off[d], e1 = off[d + 1];
    int np  = (e1 - e0) >> 1;
    int rem = (e1 - e0) & 1;
    // init: half 0 takes the self row; half 1 takes the odd tail edge
    int s_init = half ? (rem ? (int)csr16[e1 - 1] : -1) : d;
    float a0 = 0.f, a1 = 0.f, a2 = 0.f, a3 = 0.f;
    if (s_init >= 0) {
      uint2 vv = Tw2[s_init * 32 + li];
      a0 = plo(vv.x); a1 = phi(vv.x); a2 = plo(vv.y); a3 = phi(vv.y);
    }
    int st = 0;
    int base = e0 + half;
    for (; st + 4 <= np; st += 4) {
      int s0 = csr16[base + 2 * st];
      int s1 = csr16[base + 2 * st + 2];
      int s2 = csr16[base + 2 * st + 4];
      int s3 = csr16[base + 2 * st + 6];
      uint2 v0 = Tw2[s0 * 32 + li];
      uint2 v1 = Tw2[s1 * 32 + li];
      uint2 v2 = Tw2[s2 * 32 + li];
      uint2 v3 = Tw2[s3 * 32 + li];
      a0 += plo(v0.x); a1 += phi(v0.x); a2 += plo(v0.y); a3 += phi(v0.y);
      a0 += plo(v1.x); a1 += phi(v1.x); a2 += plo(v1.y); a3 += phi(v1.y);
      a0 += plo(v2.x); a1 += phi(v2.x); a2 += plo(v2.y); a3 += phi(v2.y);
      a0 += plo(v3.x); a1 += phi(v3.x); a2 += plo(v3.y); a3 += phi(v3.y);
    }
    for (; st < np; ++st) {
      int s = csr16[base + 2 * st];
      uint2 vv = Tw2[s * 32 + li];
      a0 += plo(vv.x); a1 += phi(vv.x); a2 += plo(vv.y); a3 += phi(vv.y);
    }
    // cross-half reduce: both halves end with the full sum
    a0 += __shfl_xor(a0, 32, 64);
    a1 += __shfl_xor(a1, 32, 64);
    a2 += __shfl_xor(a2, 32, 64);
    a3 += __shfl_xor(a3, 32, 64);
    float dv = dinv[d];
    a0 = fmaxf(fmaf(a0, dv, b4.x), 0.f);
    a1 = fmaxf(fmaf(a1, dv, b4.y), 0.f);
    a2 = fmaxf(fmaf(a2, dv, b4.z), 0.f);
    a3 = fmaxf(fmaf(a3, dv, b4.w), 0.f);
    if (FINAL) {
      float r = a0 * w4.x + a1 * w4.y + a2 * w4.z + a3 * w4.w;
      r += __shfl_xor(r, 16, 64);
      r += __shfl_xor(r, 8, 64);
      r += __shfl_xor(r, 4, 64);
      r += __shfl_xor(r, 2, 64);
      r += __shfl_xor(r, 1, 64);
      if (lane == 0) ((float*)outp)[d] = 1.f / (1.f + __expf(-(r + bout[0])));
    } else {
      if (half == 0) {
        uint2 o;
        o.x = (unsigned)f2b(a0) | ((unsigned)f2b(a1) << 16);
        o.y = (unsigned)f2b(a2) | ((unsigned)f2b(a3) << 16);
        ((uint2*)outp)[d * 32 + li] = o;
      }
    }
  }
}

// ---------------------------------------------------------------------------
extern "C" void kernel_launch(void* const* d_in, const int* in_sizes, int n_in,
                              void* d_out, int out_size, void* d_ws, size_t ws_size,
                              hipStream_t stream) {
  const float* x  = (const float*)d_in[0];
  const void*  ei = d_in[1];
  const float* W1 = (const float*)d_in[2];
  const float* b1 = (const float*)d_in[3];
  const float* W2 = (const float*)d_in[4];
  const float* b2 = (const float*)d_in[5];
  const float* Wo = (const float*)d_in[6];
  const float* bo = (const float*)d_in[7];
  float* out = (float*)d_out;

  char* p = (char*)d_ws;
  auto alloc = [&](size_t bytes) {
    char* r = p;
    p += (bytes + 511) & ~(size_t)511;
    return r;
  };
  int*   bh     = (int*)alloc(sizeof(int) * NBUK * PBLK);
  int*   colsum = (int*)alloc(sizeof(int) * NBUK);
  int*   bstart = (int*)alloc(sizeof(int) * (NBUK + 1));
  int*   off    = (int*)alloc(sizeof(int) * (NN + 1));
  float* dinv   = (float*)alloc(sizeof(float) * NN);
  unsigned short* csr16 = (unsigned short*)alloc(sizeof(short) * NE);
  unsigned short* Wt1 = (unsigned short*)alloc(sizeof(short) * 128 * 128);
  unsigned short* Wt2 = (unsigned short*)alloc(sizeof(short) * 128 * 128);
  unsigned short* T   = (unsigned short*)alloc(sizeof(short) * (size_t)NN * 128);
  unsigned short* H   = (unsigned short*)alloc(sizeof(short) * (size_t)NN * 128);
  unsigned* epk = (unsigned*)T;  // 3.2 MB, dead before k_mgemm<1> writes T

  k_phist<<<PBLK, 256, 0, stream>>>(ei, bh);
  k_pscanA<<<NBUK, 256, 0, stream>>>(bh, colsum);
  k_pscanB<<<1, 256, 0, stream>>>(colsum, bstart);
  k_pscat<<<PBLK, 256, 0, stream>>>(ei, bh, bstart, epk);
  k_bofffill<<<NBUK, 256, 0, stream>>>(epk, bstart, off, dinv, csr16);
  k_wt2<<<128, 256, 0, stream>>>(W1, W2, Wt1, Wt2);

  k_mgemm<1><<<512, 256, 0, stream>>>(x, Wt1, dinv, T, NN);
  k_agg<0><<<2048, 256, 0, stream>>>(T, off, csr16, dinv, b1, nullptr, nullptr, H);
  k_mgemm<0><<<512, 256, 0, stream>>>(H, Wt2, dinv, T, NN);
  k_agg<1><<<2048, 256, 0, stream>>>(T, off, csr16, dinv, b2, Wo, bo, out);
}